// Round 1
// baseline (236.289 us; speedup 1.0000x reference)
//
#include <hip/hip_runtime.h>
#include <stdint.h>

typedef __bf16 bf16x8 __attribute__((ext_vector_type(8)));
typedef float f32x4 __attribute__((ext_vector_type(4)));

#define NSAMPLE 64
static constexpr int Bb = 4, Nn = 16384, Mm = 1024, Cc = 256;
static constexpr int K1P = 288;   // layer-1 K padded to 9*32
static constexpr int LDX1 = 296;  // LDS row stride (bf16) for X1: 592B = 148 dwords == 20 mod 32 -> 2-way
static constexpr int LDX2 = 264;  // LDS row stride for H: 528B = 132 dwords == 4 mod 32 -> 2-way

__device__ __forceinline__ unsigned short f2bf(float f) {
  unsigned int u = __builtin_bit_cast(unsigned int, f);
  u = u + 0x7fffu + ((u >> 16) & 1u);
  return (unsigned short)(u >> 16);
}

// ---------------- weight prep: fold BN into W (bf16) and bias (f32) ----------------
__global__ void prep_kernel(const float* __restrict__ W1, const float* __restrict__ b1,
                            const float* __restrict__ g1, const float* __restrict__ be1,
                            const float* __restrict__ m1, const float* __restrict__ v1,
                            const float* __restrict__ W2, const float* __restrict__ b2,
                            const float* __restrict__ g2, const float* __restrict__ be2,
                            const float* __restrict__ m2, const float* __restrict__ v2,
                            unsigned short* __restrict__ W1b, float* __restrict__ b1e,
                            unsigned short* __restrict__ W2b, float* __restrict__ b2e) {
  int t = blockIdx.x * 256 + threadIdx.x;
  if (t < 256 * K1P) {
    int o = t / K1P, k = t - o * K1P;
    float s = g1[o] / sqrtf(v1[o] + 1e-5f);
    float w = 0.f;
    // K order: k in [0,256) -> feature channel (orig col 3+k); [256,259) -> coord (orig col k-256); else 0
    if (k < 256) w = W1[o * 259 + 3 + k];
    else if (k < 259) w = W1[o * 259 + (k - 256)];
    W1b[t] = f2bf(w * s);
  }
  if (t < 256 * 256) {
    int o = t >> 8;
    float s = g2[o] / sqrtf(v2[o] + 1e-5f);
    W2b[t] = f2bf(W2[t] * s);
  }
  if (t < 256) {
    float s1 = g1[t] / sqrtf(v1[t] + 1e-5f);
    b1e[t] = s1 * (b1[t] - m1[t]) + be1[t];
    float s2 = g2[t] / sqrtf(v2[t] + 1e-5f);
    b2e[t] = s2 * (b2[t] - m2[t]) + be2[t];
  }
}

// ---------------- xyz -> float4 (x,y,z,|p|^2), |p|^2 in reference op order ----------------
__global__ void xyzw_kernel(const float* __restrict__ xyz, float4* __restrict__ xyzw) {
  int t = blockIdx.x * 256 + threadIdx.x;  // 0..B*N-1
  float x = xyz[t * 3], y = xyz[t * 3 + 1], z = xyz[t * 3 + 2];
  float pp = __fadd_rn(__fadd_rn(__fmul_rn(x, x), __fmul_rn(y, y)), __fmul_rn(z, z));
  xyzw[t] = make_float4(x, y, z, pp);
}

// ---------------- feats [B,C,N] f32 -> featsT [B,N,C] bf16 (LDS tile transpose) ----------------
__global__ void featsT_kernel(const float* __restrict__ feats, unsigned short* __restrict__ featsT) {
  __shared__ float tile[64][65];
  int bx = blockIdx.x;            // B * (N/64) * (C/64) = 4*256*4 = 4096
  int b = bx >> 10;
  int rem = bx & 1023;
  int nt = rem >> 2, ct = rem & 3;
  int t = threadIdx.x, tx = t & 63, ty = t >> 6;
  const float* src = feats + ((size_t)b * Cc + ct * 64) * Nn + nt * 64;
#pragma unroll
  for (int i = 0; i < 16; i++) {
    int c = i * 4 + ty;
    tile[c][tx] = src[(size_t)c * Nn + tx];           // coalesced in n
  }
  __syncthreads();
  unsigned short* dst = featsT + ((size_t)b * Nn + nt * 64) * Cc + ct * 64;
#pragma unroll
  for (int i = 0; i < 16; i++) {
    int n = i * 4 + ty;
    dst[(size_t)n * Cc + tx] = f2bf(tile[tx][n]);     // coalesced in c
  }
}

// ---------------- ball query: one wave per query, ordered first-64 within radius ----------------
__global__ void ballq_kernel(const float4* __restrict__ xyzw, const float* __restrict__ new_xyz,
                             int* __restrict__ idx) {
  const float r2 = (float)(0.08 * 0.08);
  int bm = blockIdx.x * 4 + (threadIdx.x >> 6);
  int lane = threadIdx.x & 63;
  int b = bm >> 10;
  float qx = new_xyz[bm * 3], qy = new_xyz[bm * 3 + 1], qz = new_xyz[bm * 3 + 2];
  float qq = __fadd_rn(__fadd_rn(__fmul_rn(qx, qx), __fmul_rn(qy, qy)), __fmul_rn(qz, qz));
  const float4* P = xyzw + (size_t)b * Nn;
  int* out = idx + (size_t)bm * NSAMPLE;
  int cnt = 0, first = 0;
  bool havef = false;
  for (int n0 = 0; n0 < Nn; n0 += 64) {
    float4 p = P[n0 + lane];
    float dt = __fadd_rn(__fadd_rn(__fmul_rn(qx, p.x), __fmul_rn(qy, p.y)), __fmul_rn(qz, p.z));
    float d2 = __fsub_rn(__fadd_rn(qq, p.w), __fmul_rn(2.f, dt));
    bool valid = d2 < r2;
    unsigned long long mask = __ballot(valid);
    if (mask) {
      if (!havef) { first = n0 + __builtin_ctzll(mask); havef = true; }
      if (valid) {
        int pos = cnt + __popcll(mask & ((1ull << lane) - 1ull));
        if (pos < NSAMPLE) out[pos] = n0 + lane;
      }
      cnt += (int)__popcll(mask);
      if (cnt >= NSAMPLE) break;
    }
  }
  int cc = cnt < NSAMPLE ? cnt : NSAMPLE;
  if (lane >= cc) out[lane] = havef ? first : 0;
}

// ---------------- fused gather + MLP1 + MLP2 + maxpool; one query per block ----------------
__global__ __launch_bounds__(256) void fused_kernel(
    const unsigned short* __restrict__ featsT, const float4* __restrict__ xyzw,
    const float* __restrict__ new_xyz, const int* __restrict__ idx,
    const unsigned short* __restrict__ W1b, const float* __restrict__ b1e,
    const unsigned short* __restrict__ W2b, const float* __restrict__ b2e,
    float* __restrict__ tmp) {
  __shared__ unsigned short X1[64 * LDX1];
  __shared__ unsigned short X2[64 * LDX2];
  __shared__ int sidx[64];
  __shared__ float q[3];
  int bm = blockIdx.x;
  int b = bm >> 10;
  int t = threadIdx.x;
  if (t < 64) sidx[t] = idx[(size_t)bm * NSAMPLE + t];
  if (t < 3) q[t] = new_xyz[bm * 3 + t];
  __syncthreads();
  // gather features: 4 threads per sample, 64 channels each, 16B chunks
  {
    int s = t >> 2, c0 = (t & 3) * 64;
    const unsigned short* src = featsT + ((size_t)b * Nn + sidx[s]) * Cc + c0;
    unsigned short* dst = &X1[s * LDX1 + c0];
#pragma unroll
    for (int i = 0; i < 8; i++)
      *(uint4*)(dst + i * 8) = *(const uint4*)(src + i * 8);
  }
  // relative coords + zero pad
  if (t < 64) {
    float4 p = xyzw[(size_t)b * Nn + sidx[t]];
    unsigned short* row = &X1[t * LDX1];
    row[256] = f2bf(p.x - q[0]);
    row[257] = f2bf(p.y - q[1]);
    row[258] = f2bf(p.z - q[2]);
#pragma unroll
    for (int j = 259; j < K1P; j++) row[j] = 0;
  }
  __syncthreads();

  int wave = t >> 6, lane = t & 63;
  int lr = lane & 15, kg = lane >> 4;
  int wcol = wave * 64;

  // ---- layer 1: [64 x 288] x [288 x 256] ----
  f32x4 acc[4][4];
#pragma unroll
  for (int mi = 0; mi < 4; mi++)
#pragma unroll
    for (int ni = 0; ni < 4; ni++) acc[mi][ni] = (f32x4){0.f, 0.f, 0.f, 0.f};
#pragma unroll
  for (int kk = 0; kk < K1P / 32; kk++) {
    int ks = kk * 32 + kg * 8;
    bf16x8 a[4], w[4];
#pragma unroll
    for (int mi = 0; mi < 4; mi++)
      a[mi] = *(const bf16x8*)&X1[(mi * 16 + lr) * LDX1 + ks];
#pragma unroll
    for (int ni = 0; ni < 4; ni++)
      w[ni] = *(const bf16x8*)&W1b[(size_t)(wcol + ni * 16 + lr) * K1P + ks];
#pragma unroll
    for (int mi = 0; mi < 4; mi++)
#pragma unroll
      for (int ni = 0; ni < 4; ni++)
        acc[mi][ni] = __builtin_amdgcn_mfma_f32_16x16x32_bf16(a[mi], w[ni], acc[mi][ni], 0, 0, 0);
  }
  // epilogue 1: bias + relu -> X2 (bf16)
  {
    float bb[4];
#pragma unroll
    for (int ni = 0; ni < 4; ni++) bb[ni] = b1e[wcol + ni * 16 + lr];
#pragma unroll
    for (int mi = 0; mi < 4; mi++)
#pragma unroll
      for (int ni = 0; ni < 4; ni++)
#pragma unroll
        for (int j = 0; j < 4; j++) {
          int row = mi * 16 + kg * 4 + j;
          float h = fmaxf(acc[mi][ni][j] + bb[ni], 0.f);
          X2[row * LDX2 + wcol + ni * 16 + lr] = f2bf(h);
        }
  }
  __syncthreads();

  // ---- layer 2: [64 x 256] x [256 x 256] ----
  f32x4 acc2[4][4];
#pragma unroll
  for (int mi = 0; mi < 4; mi++)
#pragma unroll
    for (int ni = 0; ni < 4; ni++) acc2[mi][ni] = (f32x4){0.f, 0.f, 0.f, 0.f};
#pragma unroll
  for (int kk = 0; kk < 8; kk++) {
    int ks = kk * 32 + kg * 8;
    bf16x8 a[4], w[4];
#pragma unroll
    for (int mi = 0; mi < 4; mi++)
      a[mi] = *(const bf16x8*)&X2[(mi * 16 + lr) * LDX2 + ks];
#pragma unroll
    for (int ni = 0; ni < 4; ni++)
      w[ni] = *(const bf16x8*)&W2b[(size_t)(wcol + ni * 16 + lr) * 256 + ks];
#pragma unroll
    for (int mi = 0; mi < 4; mi++)
#pragma unroll
      for (int ni = 0; ni < 4; ni++)
        acc2[mi][ni] = __builtin_amdgcn_mfma_f32_16x16x32_bf16(a[mi], w[ni], acc2[mi][ni], 0, 0, 0);
  }
  // epilogue 2: bias + relu + max over 64 samples -> tmp[b][m][o]
#pragma unroll
  for (int ni = 0; ni < 4; ni++) {
    float bv = b2e[wcol + ni * 16 + lr];
    float v = 0.f;  // relu(max) == max(relu); 0 init covers all-negative case
#pragma unroll
    for (int mi = 0; mi < 4; mi++)
#pragma unroll
      for (int j = 0; j < 4; j++) v = fmaxf(v, acc2[mi][ni][j] + bv);
    v = fmaxf(v, __shfl_xor(v, 16));
    v = fmaxf(v, __shfl_xor(v, 32));
    if (kg == 0) tmp[(size_t)bm * 256 + wcol + ni * 16 + lr] = v;
  }
}

// ---------------- tmp [B,M,256] -> out [B,256,M] ----------------
__global__ void outT_kernel(const float* __restrict__ tmp, float* __restrict__ out) {
  __shared__ float tile[64][65];
  int bx = blockIdx.x;         // B * (M/64) * (C/64) = 4*16*4 = 256
  int b = bx >> 6;
  int rem = bx & 63;
  int mt = rem >> 2, ot = rem & 3;
  int t = threadIdx.x, tx = t & 63, ty = t >> 6;
#pragma unroll
  for (int i = 0; i < 16; i++) {
    int mi = i * 4 + ty;
    tile[mi][tx] = tmp[((size_t)b * Mm + mt * 64 + mi) * 256 + ot * 64 + tx];
  }
  __syncthreads();
#pragma unroll
  for (int i = 0; i < 16; i++) {
    int oi = i * 4 + ty;
    out[((size_t)b * 256 + ot * 64 + oi) * Mm + mt * 64 + tx] = tile[tx][oi];
  }
}

extern "C" void kernel_launch(void* const* d_in, const int* in_sizes, int n_in,
                              void* d_out, int out_size, void* d_ws, size_t ws_size,
                              hipStream_t stream) {
  (void)in_sizes; (void)n_in; (void)out_size; (void)ws_size;
  const float* xyz     = (const float*)d_in[0];   // [4,16384,3]
  const float* new_xyz = (const float*)d_in[1];   // [4,1024,3]
  const float* feats   = (const float*)d_in[2];   // [4,256,16384]
  const float* W1 = (const float*)d_in[3];
  const float* b1 = (const float*)d_in[4];
  const float* g1 = (const float*)d_in[5];
  const float* be1 = (const float*)d_in[6];
  const float* m1 = (const float*)d_in[7];
  const float* v1 = (const float*)d_in[8];
  const float* W2 = (const float*)d_in[9];
  const float* b2 = (const float*)d_in[10];
  const float* g2 = (const float*)d_in[11];
  const float* be2 = (const float*)d_in[12];
  const float* m2 = (const float*)d_in[13];
  const float* v2 = (const float*)d_in[14];
  float* out = (float*)d_out;

  char* ws = (char*)d_ws;
  unsigned short* W1b   = (unsigned short*)(ws + 0);         // 147456 B
  unsigned short* W2b   = (unsigned short*)(ws + 147456);    // 131072 B
  float*          b1e   = (float*)(ws + 278528);             // 1024 B
  float*          b2e   = (float*)(ws + 279552);             // 1024 B
  float4*         xyzw  = (float4*)(ws + 280576);            // 1048576 B
  unsigned short* featsT= (unsigned short*)(ws + 1329152);   // 33554432 B
  int*            idx   = (int*)(ws + 34883584);             // 1048576 B
  float*          tmp   = (float*)(ws + 35932160);           // 4194304 B  (end ~40.1MB)

  prep_kernel<<<(256 * K1P + 255) / 256, 256, 0, stream>>>(
      W1, b1, g1, be1, m1, v1, W2, b2, g2, be2, m2, v2, W1b, b1e, W2b, b2e);
  xyzw_kernel<<<(Bb * Nn) / 256, 256, 0, stream>>>(xyz, xyzw);
  featsT_kernel<<<Bb * (Nn / 64) * (Cc / 64), 256, 0, stream>>>(feats, featsT);
  ballq_kernel<<<(Bb * Mm) / 4, 256, 0, stream>>>(xyzw, new_xyz, idx);
  fused_kernel<<<Bb * Mm, 256, 0, stream>>>(featsT, xyzw, new_xyz, idx, W1b, b1e, W2b, b2e, tmp);
  outT_kernel<<<Bb * (Mm / 64) * (Cc / 64), 256, 0, stream>>>(tmp, out);
}

// Round 5
// 223.571 us; speedup vs baseline: 1.0569x; 1.0569x over previous
//
#include <hip/hip_runtime.h>
#include <stdint.h>

typedef __bf16 bf16x8 __attribute__((ext_vector_type(8)));
typedef float f32x4 __attribute__((ext_vector_type(4)));

#define NSAMPLE 64
static constexpr int Bb = 4, Nn = 16384, Mm = 1024, Cc = 256;
static constexpr int K1P = 288;   // layer-1 K padded to 9*32
static constexpr int LDX1 = 296;  // u16 stride; 592B rows (16B-aligned)
static constexpr int LDX2 = 264;  // u16 stride; 528B rows (16B-aligned)
// LDS row strides in u16 must stay multiples of 8 (16B alignment for ds_read_b128).

__device__ __forceinline__ unsigned short f2bf(float f) {
  unsigned int u = __builtin_bit_cast(unsigned int, f);
  u = u + 0x7fffu + ((u >> 16) & 1u);
  return (unsigned short)(u >> 16);
}

// ---------------- weight prep: fold BN into W (bf16) and bias (f32) — R1 verbatim ----------------
__global__ void prep_kernel(const float* __restrict__ W1, const float* __restrict__ b1,
                            const float* __restrict__ g1, const float* __restrict__ be1,
                            const float* __restrict__ m1, const float* __restrict__ v1,
                            const float* __restrict__ W2, const float* __restrict__ b2,
                            const float* __restrict__ g2, const float* __restrict__ be2,
                            const float* __restrict__ m2, const float* __restrict__ v2,
                            unsigned short* __restrict__ W1b, float* __restrict__ b1e,
                            unsigned short* __restrict__ W2b, float* __restrict__ b2e) {
  int t = blockIdx.x * 256 + threadIdx.x;
  if (t < 256 * K1P) {
    int o = t / K1P, k = t - o * K1P;
    float s = g1[o] / sqrtf(v1[o] + 1e-5f);
    float w = 0.f;
    if (k < 256) w = W1[o * 259 + 3 + k];
    else if (k < 259) w = W1[o * 259 + (k - 256)];
    W1b[t] = f2bf(w * s);
  }
  if (t < 256 * 256) {
    int o = t >> 8;
    float s = g2[o] / sqrtf(v2[o] + 1e-5f);
    W2b[t] = f2bf(W2[t] * s);
  }
  if (t < 256) {
    float s1 = g1[t] / sqrtf(v1[t] + 1e-5f);
    b1e[t] = s1 * (b1[t] - m1[t]) + be1[t];
    float s2 = g2[t] / sqrtf(v2[t] + 1e-5f);
    b2e[t] = s2 * (b2[t] - m2[t]) + be2[t];
  }
}

// ---------------- xyz -> float4 (x,y,z,|p|^2) — R1 verbatim (separate kernel) ----------------
__global__ void xyzw_kernel(const float* __restrict__ xyz, float4* __restrict__ xyzw) {
  int t = blockIdx.x * 256 + threadIdx.x;  // 0..B*N-1
  float x = xyz[t * 3], y = xyz[t * 3 + 1], z = xyz[t * 3 + 2];
  float pp = __fadd_rn(__fadd_rn(__fmul_rn(x, x), __fmul_rn(y, y)), __fmul_rn(z, z));
  xyzw[t] = make_float4(x, y, z, pp);
}

// ---------------- feats [B,C,N] f32 -> featsT [B,N,C] bf16 — R1 verbatim ----------------
__global__ void featsT_kernel(const float* __restrict__ feats, unsigned short* __restrict__ featsT) {
  __shared__ float tile[64][65];
  int bx = blockIdx.x;            // 4*256*4 = 4096
  int b = bx >> 10;
  int rem = bx & 1023;
  int nt = rem >> 2, ct = rem & 3;
  int t = threadIdx.x, tx = t & 63, ty = t >> 6;
  const float* src = feats + ((size_t)b * Cc + ct * 64) * Nn + nt * 64;
#pragma unroll
  for (int i = 0; i < 16; i++) {
    int c = i * 4 + ty;
    tile[c][tx] = src[(size_t)c * Nn + tx];
  }
  __syncthreads();
  unsigned short* dst = featsT + ((size_t)b * Nn + nt * 64) * Cc + ct * 64;
#pragma unroll
  for (int i = 0; i < 16; i++) {
    int n = i * 4 + ty;
    dst[(size_t)n * Cc + tx] = f2bf(tile[tx][n]);
  }
}

// ---------------- ball query — R1 verbatim (NO prefetch) ----------------
__global__ void ballq_kernel(const float4* __restrict__ xyzw, const float* __restrict__ new_xyz,
                             int* __restrict__ idx) {
  const float r2 = (float)(0.08 * 0.08);
  int bm = blockIdx.x * 4 + (threadIdx.x >> 6);
  int lane = threadIdx.x & 63;
  int b = bm >> 10;
  float qx = new_xyz[bm * 3], qy = new_xyz[bm * 3 + 1], qz = new_xyz[bm * 3 + 2];
  float qq = __fadd_rn(__fadd_rn(__fmul_rn(qx, qx), __fmul_rn(qy, qy)), __fmul_rn(qz, qz));
  const float4* P = xyzw + (size_t)b * Nn;
  int* out = idx + (size_t)bm * NSAMPLE;
  int cnt = 0, first = 0;
  bool havef = false;
  for (int n0 = 0; n0 < Nn; n0 += 64) {
    float4 p = P[n0 + lane];
    float dt = __fadd_rn(__fadd_rn(__fmul_rn(qx, p.x), __fmul_rn(qy, p.y)), __fmul_rn(qz, p.z));
    float d2 = __fsub_rn(__fadd_rn(qq, p.w), __fmul_rn(2.f, dt));
    bool valid = d2 < r2;
    unsigned long long mask = __ballot(valid);
    if (mask) {
      if (!havef) { first = n0 + __builtin_ctzll(mask); havef = true; }
      if (valid) {
        int pos = cnt + __popcll(mask & ((1ull << lane) - 1ull));
        if (pos < NSAMPLE) out[pos] = n0 + lane;
      }
      cnt += (int)__popcll(mask);
      if (cnt >= NSAMPLE) break;
    }
  }
  int cc = cnt < NSAMPLE ? cnt : NSAMPLE;
  if (lane >= cc) out[lane] = havef ? first : 0;
}

// ---------------- fused: 1 query/block, 256 thr; X2 aliases X1; direct out ----------------
__global__ __launch_bounds__(256, 4) void fused_kernel(
    const unsigned short* __restrict__ featsT, const float4* __restrict__ xyzw,
    const float* __restrict__ new_xyz, const int* __restrict__ idx,
    const unsigned short* __restrict__ W1b, const float* __restrict__ b1e,
    const unsigned short* __restrict__ W2b, const float* __restrict__ b2e,
    float* __restrict__ out) {
  __shared__ unsigned short X[64 * LDX1];  // phase 1: stride LDX1; phase 2: stride LDX2
  __shared__ int sidx[64];
  __shared__ float q[3];
  int bm = blockIdx.x;
  int b = bm >> 10;
  int t = threadIdx.x;
  if (t < 64) sidx[t] = idx[(size_t)bm * NSAMPLE + t];
  if (t < 3) q[t] = new_xyz[bm * 3 + t];
  __syncthreads();
  // gather features: 4 threads per sample, 64 channels each, 16B chunks
  {
    int s = t >> 2, c0 = (t & 3) * 64;
    const unsigned short* src = featsT + ((size_t)b * Nn + sidx[s]) * Cc + c0;
    unsigned short* dst = &X[s * LDX1 + c0];
#pragma unroll
    for (int i = 0; i < 8; i++)
      *(uint4*)(dst + i * 8) = *(const uint4*)(src + i * 8);
  }
  // relative coords + zero pad
  if (t < 64) {
    float4 p = xyzw[(size_t)b * Nn + sidx[t]];
    unsigned short* row = &X[t * LDX1];
    row[256] = f2bf(p.x - q[0]);
    row[257] = f2bf(p.y - q[1]);
    row[258] = f2bf(p.z - q[2]);
#pragma unroll
    for (int j = 259; j < K1P; j++) row[j] = 0;
  }
  __syncthreads();

  int wave = t >> 6, lane = t & 63;
  int lr = lane & 15, kg = lane >> 4;
  int wcol = wave * 64;

  // ---- layer 1: [64 x 288] x [288 x 256] ----
  f32x4 acc[4][4];
#pragma unroll
  for (int mi = 0; mi < 4; mi++)
#pragma unroll
    for (int ni = 0; ni < 4; ni++) acc[mi][ni] = (f32x4){0.f, 0.f, 0.f, 0.f};
#pragma unroll
  for (int kk = 0; kk < K1P / 32; kk++) {
    int ks = kk * 32 + kg * 8;
    bf16x8 a[4], w[4];
#pragma unroll
    for (int mi = 0; mi < 4; mi++)
      a[mi] = *(const bf16x8*)&X[(mi * 16 + lr) * LDX1 + ks];
#pragma unroll
    for (int ni = 0; ni < 4; ni++)
      w[ni] = *(const bf16x8*)&W1b[(size_t)(wcol + ni * 16 + lr) * K1P + ks];
#pragma unroll
    for (int mi = 0; mi < 4; mi++)
#pragma unroll
      for (int ni = 0; ni < 4; ni++)
        acc[mi][ni] = __builtin_amdgcn_mfma_f32_16x16x32_bf16(a[mi], w[ni], acc[mi][ni], 0, 0, 0);
  }
  __syncthreads();  // ALL waves done reading X (stride LDX1) before epi-1 overwrites (stride LDX2)
  // epilogue 1: bias + relu -> X (bf16, stride LDX2)
  {
    float bb[4];
#pragma unroll
    for (int ni = 0; ni < 4; ni++) bb[ni] = b1e[wcol + ni * 16 + lr];
#pragma unroll
    for (int mi = 0; mi < 4; mi++)
#pragma unroll
      for (int ni = 0; ni < 4; ni++)
#pragma unroll
        for (int j = 0; j < 4; j++) {
          int row = mi * 16 + kg * 4 + j;
          float h = fmaxf(acc[mi][ni][j] + bb[ni], 0.f);
          X[row * LDX2 + wcol + ni * 16 + lr] = f2bf(h);
        }
  }
  __syncthreads();

  // ---- layer 2: [64 x 256] x [256 x 256] ----
  f32x4 acc2[4][4];
#pragma unroll
  for (int mi = 0; mi < 4; mi++)
#pragma unroll
    for (int ni = 0; ni < 4; ni++) acc2[mi][ni] = (f32x4){0.f, 0.f, 0.f, 0.f};
#pragma unroll
  for (int kk = 0; kk < 8; kk++) {
    int ks = kk * 32 + kg * 8;
    bf16x8 a[4], w[4];
#pragma unroll
    for (int mi = 0; mi < 4; mi++)
      a[mi] = *(const bf16x8*)&X[(mi * 16 + lr) * LDX2 + ks];
#pragma unroll
    for (int ni = 0; ni < 4; ni++)
      w[ni] = *(const bf16x8*)&W2b[(size_t)(wcol + ni * 16 + lr) * 256 + ks];
#pragma unroll
    for (int mi = 0; mi < 4; mi++)
#pragma unroll
      for (int ni = 0; ni < 4; ni++)
        acc2[mi][ni] = __builtin_amdgcn_mfma_f32_16x16x32_bf16(a[mi], w[ni], acc2[mi][ni], 0, 0, 0);
  }
  // epilogue 2: bias + relu + max over 64 samples -> out[b][o][m] directly
  {
    int m = bm & (Mm - 1);
#pragma unroll
    for (int ni = 0; ni < 4; ni++) {
      float bv = b2e[wcol + ni * 16 + lr];
      float v = 0.f;  // relu(max) == max(relu)
#pragma unroll
      for (int mi = 0; mi < 4; mi++)
#pragma unroll
        for (int j = 0; j < 4; j++) v = fmaxf(v, acc2[mi][ni][j] + bv);
      v = fmaxf(v, __shfl_xor(v, 16));
      v = fmaxf(v, __shfl_xor(v, 32));
      if (kg == 0)
        out[((size_t)b * 256 + wcol + ni * 16 + lr) * Mm + m] = v;
    }
  }
}

extern "C" void kernel_launch(void* const* d_in, const int* in_sizes, int n_in,
                              void* d_out, int out_size, void* d_ws, size_t ws_size,
                              hipStream_t stream) {
  (void)in_sizes; (void)n_in; (void)out_size; (void)ws_size;
  const float* xyz     = (const float*)d_in[0];
  const float* new_xyz = (const float*)d_in[1];
  const float* feats   = (const float*)d_in[2];
  const float* W1 = (const float*)d_in[3];
  const float* b1 = (const float*)d_in[4];
  const float* g1 = (const float*)d_in[5];
  const float* be1 = (const float*)d_in[6];
  const float* m1 = (const float*)d_in[7];
  const float* v1 = (const float*)d_in[8];
  const float* W2 = (const float*)d_in[9];
  const float* b2 = (const float*)d_in[10];
  const float* g2 = (const float*)d_in[11];
  const float* be2 = (const float*)d_in[12];
  const float* m2 = (const float*)d_in[13];
  const float* v2 = (const float*)d_in[14];
  float* out = (float*)d_out;

  char* ws = (char*)d_ws;
  unsigned short* W1b   = (unsigned short*)(ws + 0);         // 147456 B
  unsigned short* W2b   = (unsigned short*)(ws + 147456);    // 131072 B
  float*          b1e   = (float*)(ws + 278528);             // 1024 B
  float*          b2e   = (float*)(ws + 279552);             // 1024 B
  float4*         xyzw  = (float4*)(ws + 280576);            // 1048576 B
  unsigned short* featsT= (unsigned short*)(ws + 1329152);   // 33554432 B
  int*            idx   = (int*)(ws + 34883584);             // 1048576 B

  prep_kernel<<<(256 * K1P + 255) / 256, 256, 0, stream>>>(
      W1, b1, g1, be1, m1, v1, W2, b2, g2, be2, m2, v2, W1b, b1e, W2b, b2e);
  xyzw_kernel<<<(Bb * Nn) / 256, 256, 0, stream>>>(xyz, xyzw);
  featsT_kernel<<<Bb * (Nn / 64) * (Cc / 64), 256, 0, stream>>>(feats, featsT);
  ballq_kernel<<<(Bb * Mm) / 4, 256, 0, stream>>>(xyzw, new_xyz, idx);
  fused_kernel<<<Bb * Mm, 256, 0, stream>>>(featsT, xyzw, new_xyz, idx, W1b, b1e, W2b, b2e, out);
}